// Round 15
// baseline (364.496 us; speedup 1.0000x reference)
//
#include <hip/hip_runtime.h>

#define T 32
#define B 256

typedef int v4i __attribute__((ext_vector_type(4)));

// ---------------- workspace byte offsets ----------------
#define OFF_BD2   0            // int8 [4][9][128][64]  conv2 digits    (5-plane slot)
#define OFF_BD3   368640       // int8 [4][18][256][64] conv3 digits
#define OFF_BDTC  1843200      // int8 [4][12][256][64] tc digits
#define OFF_BDF1  2826240      // int8 [4][4][128][64]  fc1 digits
#define OFF_BDREC 2990080      // int8 [4][256][256]   rec digits
#define OFF_S1    3514368      // uchar [T][B][pix64][ic64]           33,554,432
#define OFF_POOL  37068800     // uchar [w9][t32][b256][oc128]         9,437,184
#define OFF_PSP3  46505984     // double [8192][256]                  16,777,216
#define OFF_S3    63283200     // uchar [t][b][256]                    2,097,152
#define OFF_PSPTC 65380352     // double [8192][256]                  16,777,216
#define OFF_R     84254720     // uchar [t][b][256]                    2,097,152
#define OFF_PSPF1 OFF_PSPTC    // double [8192][128] — reuses psptc (retired)
// total 86,351,872 bytes

// ---------------- fused prepd + conv1 (independent work, one dispatch) ----------
__global__ __launch_bounds__(256) void k_prep_conv1(const float* __restrict__ x,
        const float* __restrict__ w1, const float* __restrict__ b1,
        unsigned char* __restrict__ s1,
        const float* __restrict__ c2w, const float* __restrict__ c3w,
        const float* __restrict__ tcw, const float* __restrict__ f1w,
        const float* __restrict__ rcw,
        signed char* __restrict__ Bd2, signed char* __restrict__ Bd3,
        signed char* __restrict__ Bdtc, signed char* __restrict__ Bdf1,
        signed char* __restrict__ Bdrec) {
    __shared__ float xl[3200];              // [pos][t] (conv1 blocks only)
    if (blockIdx.x >= 1024) {               // ---- prepd path ----
        int idx = (blockIdx.x - 1024) * 256 + threadIdx.x;
        float w; signed char* base; int plane, off;
        if (idx < 73728) {                       // conv2: off = (kk*128+oc)*64+ic
            int oc = idx / 576, kpos = idx - oc * 576;
            int kk = kpos >> 6, ic = kpos & 63;
            int ky = kk / 3, kx = kk - ky * 3;
            w = c2w[((oc * 64 + ic) * 3 + ky) * 3 + kx];
            base = Bd2; plane = 73728; off = (kk * 128 + oc) * 64 + ic;
        } else if (idx < 368640) {               // conv3: k = win*128+ic
            int m = idx - 73728;
            int oc = m / 1152, kpos = m - oc * 1152;
            int win = kpos >> 7, ic = kpos & 127;
            w = c3w[(oc * 128 + ic) * 9 + win];
            base = Bd3; plane = 294912;
            off = ((kpos >> 6) * 256 + oc) * 64 + (kpos & 63);
        } else if (idx < 565248) {               // tc: k = j*256+kc
            int m = idx - 368640;
            int oc = m / 768, kpos = m - oc * 768;
            int j = kpos >> 8, kc = kpos & 255;
            w = tcw[(j * 256 + oc) * 256 + kc];
            base = Bdtc; plane = 196608;
            off = ((kpos >> 6) * 256 + oc) * 64 + (kpos & 63);
        } else if (idx < 598016) {               // fc1: k = kc
            int m = idx - 565248;
            int oc = m >> 8, kc = m & 255;
            w = f1w[oc * 256 + kc];
            base = Bdf1; plane = 32768;
            off = ((kc >> 6) * 128 + oc) * 64 + (kc & 63);
        } else if (idx < 663552) {               // rec: [d][oc][k]
            int m = idx - 598016;
            int oc = m >> 8, k = m & 255;
            w = rcw[oc * 256 + k];
            base = Bdrec; plane = 65536; off = m;
        } else return;
        long long W = (long long)rint((double)w * 2147483648.0);   // 2^31
#pragma unroll
        for (int d = 0; d < 3; ++d) {
            int dig = (int)(((W + 128) & 255) - 128);
            base[d * plane + off] = (signed char)dig;
            W = (W - dig) >> 8;
        }
        base[3 * plane + off] = (signed char)W;
        return;
    }
    // ---- conv1 path: LDS [pos][t] direct copy, t-vectorized taps ----
    int b  = blockIdx.x >> 2;
    int bp = blockIdx.x & 3;
    int oc = threadIdx.x & 63;
    int sub = threadIdx.x >> 6;             // 0..3
    const float* xb = x + b * 3200;         // input_data[b][0][10][10][T], t innermost
    for (int i = threadIdx.x; i < 3200; i += 256)
        xl[i] = xb[i];
    double wd[9];
#pragma unroll
    for (int j = 0; j < 9; ++j) wd[j] = (double)w1[oc * 9 + j];
    double bias = (double)b1[oc];
    __syncthreads();
    double cur[4], vlt[4];
    unsigned spkb = 0;
#pragma unroll
    for (int i = 0; i < 4; ++i) { cur[i] = 0.0; vlt[i] = 0.0; }
    const int pixbase = bp * 16 + sub * 4;
#pragma unroll 1
    for (int tb = 0; tb < 8; ++tb) {
#pragma unroll
        for (int i = 0; i < 4; ++i) {
            int pix = pixbase + i;
            int oy = pix >> 3, ox = pix & 7;
            double z0 = bias, z1 = bias, z2 = bias, z3 = bias;
#pragma unroll
            for (int ky = 0; ky < 3; ++ky)
#pragma unroll
                for (int kx = 0; kx < 3; ++kx) {
                    float4 v = *(const float4*)(&xl[((oy + ky) * 10 + ox + kx) * 32 + tb * 4]);
                    double w = wd[ky * 3 + kx];
                    z0 = fma(w, (double)v.x, z0);
                    z1 = fma(w, (double)v.y, z1);
                    z2 = fma(w, (double)v.z, z2);
                    z3 = fma(w, (double)v.w, z3);
                }
            double z[4] = { z0, z1, z2, z3 };
#pragma unroll
            for (int j = 0; j < 4; ++j) {
                int t = tb * 4 + j;
                cur[i] = 0.5 * cur[i] + z[j];
                int s = (spkb >> i) & 1;
                vlt[i] = (s ? 0.0 : 0.75 * vlt[i]) + cur[i];
                s = (vlt[i] > 0.5) ? 1 : 0;
                spkb = (spkb & ~(1u << i)) | ((unsigned)s << i);
                s1[((size_t)(t * B + b) * 64 + pix) * 64 + oc] = (unsigned char)s;
            }
        }
    }
}

// ---------------- conv2: single-pass 4-digit MFMA + in-register LIF ------------
// (R9 form — measured local optimum 98.7-99.5 µs.)
__global__ __launch_bounds__(256, 2) void k_conv2(const unsigned char* __restrict__ s1,
        const signed char* __restrict__ Bd2, const float* __restrict__ cb2,
        unsigned char* __restrict__ pooled) {
    __shared__ __align__(16) unsigned char As[32 * 1024];   // [t][swz(p,qo)][16]
    __shared__ unsigned smask[2][4][64];
    const int b = blockIdx.x / 9;
    const int w = blockIdx.x - b * 9;
    const int wy = w / 3, wx = w - wy * 3;
    const int tid = threadIdx.x;
    const int wave = tid >> 6, lane = tid & 63;
    const int col = lane & 15, quad = lane >> 4;
    const int m = lane & 15;
    const int px = m >> 2, tq = m & 3;          // A-row: px major, t minor
    const int py0 = px >> 1, px0 = px & 1;

    {   // stage A: p varies fastest across lanes (2-way-free write phases)
        const int pixbase = (2 * wy) * 8 + 2 * wx;
        for (int c = tid; c < 2048; c += 256) {
            int t = c >> 6, rem = c & 63;
            int p = rem & 15, qo = rem >> 4;
            int ly = p >> 2, lx = p & 3;
            int pix = pixbase + ly * 8 + lx;
            v4i v = *(const v4i*)(s1 + (((size_t)(t * B + b) * 64 + pix) << 6) + qo * 16);
            *(v4i*)(As + t * 1024 + ((qo * 16) + (p ^ (2 * (t & 3)))) * 16) = v;
        }
    }
    __syncthreads();

    for (int nh = 0; nh < 2; ++nh) {
        const int oc = nh * 64 + wave * 16 + col;
        const int boff = oc * 64 + quad * 16;       // lane offset within a kk slab
        v4i acc[8][4];
#pragma unroll
        for (int mt = 0; mt < 8; ++mt)
#pragma unroll
            for (int d = 0; d < 4; ++d) acc[mt][d] = (v4i){0, 0, 0, 0};
        v4i Bc[4], Bn[4];
#pragma unroll
        for (int d = 0; d < 4; ++d)
            Bc[d] = *(const v4i*)(Bd2 + (size_t)d * 73728 + boff);
#pragma unroll 1
        for (int kk = 0; kk < 9; ++kk) {
            if (kk < 8) {
#pragma unroll
                for (int d = 0; d < 4; ++d)
                    Bn[d] = *(const v4i*)(Bd2 + (size_t)d * 73728 + (kk + 1) * 8192 + boff);
            }
            const int ky = kk / 3, kx = kk - ky * 3;
            const int p = (py0 + ky) * 4 + (px0 + kx);
            const unsigned char* Ab = As + tq * 1024 + (quad * 16 + (p ^ (2 * tq))) * 16;
#pragma unroll
            for (int mt = 0; mt < 8; ++mt) {
                v4i Af = *(const v4i*)(Ab + mt * 4096);   // t = 4*mt + tq
#pragma unroll
                for (int d = 0; d < 4; ++d)
                    acc[mt][d] = __builtin_amdgcn_mfma_i32_16x16x64_i8(Af, Bc[d], acc[mt][d], 0, 0, 0);
            }
            if (kk < 8) {
#pragma unroll
                for (int d = 0; d < 4; ++d) Bc[d] = Bn[d];
            }
        }
        // in-register LIF: exact integer-pair recombine.
        double cur = 0.0, vlt = 0.0;
        int spk = 0;
        unsigned bits = 0;
        double bias = (double)cb2[oc];
#pragma unroll
        for (int mt = 0; mt < 8; ++mt)
#pragma unroll
            for (int r = 0; r < 4; ++r) {
                int lo = acc[mt][0][r] + (acc[mt][1][r] << 8);
                int hi = acc[mt][2][r] + (acc[mt][3][r] << 8);
                double v = fma((double)hi, 65536.0, (double)lo);
                double z = fma(v, 0x1p-31, bias);
                cur = 0.5 * cur + z;
                vlt = (spk ? 0.0 : 0.75 * vlt) + cur;
                spk = (vlt > 0.5) ? 1 : 0;
                bits |= ((unsigned)spk) << (mt * 4 + r);
            }
        smask[nh][quad][wave * 16 + col] = bits;
        __syncthreads();
        {   // avgpool: lane (quad,col) handles t = quad*8..quad*8+7 for its oc
            unsigned m0 = smask[nh][0][wave * 16 + col], m1 = smask[nh][1][wave * 16 + col];
            unsigned m2 = smask[nh][2][wave * 16 + col], m3 = smask[nh][3][wave * 16 + col];
#pragma unroll
            for (int q = 0; q < 8; ++q) {
                int t = quad * 8 + q;
                unsigned s = ((m0 >> t) & 1) + ((m1 >> t) & 1) + ((m2 >> t) & 1) + ((m3 >> t) & 1);
                pooled[(size_t)((w * 32 + t) * 256 + b) * 128 + oc] = (unsigned char)s;
            }
        }
    }
}

// ---------------- conv3 PSP: 4-digit i8 GEMM, 512 threads (8 waves, N=32/wave) --
__global__ __launch_bounds__(512) void k_c3psp(const unsigned char* __restrict__ pooled,
        const signed char* __restrict__ Bd3, const float* __restrict__ b3,
        double* __restrict__ psp) {
    __shared__ __align__(16) unsigned char As[32 * 1168];   // row pad 16
    const int mt = blockIdx.x, rbase = mt * 32;
    const int tid = threadIdx.x;
    const int wave = tid >> 6, lane = tid & 63;
    const int col = lane & 15, quad = lane >> 4;
    for (int c = tid; c < 2304; c += 512) {       // 32 rows x 72 chunks
        int row = c / 72, cho = c - row * 72;
        int wn = cho >> 3, ico = (cho & 7) * 16;
        v4i v = *(const v4i*)(pooled + ((size_t)(wn * 8192) + rbase + row) * 128 + ico);
        *(v4i*)(As + row * 1168 + cho * 16) = v;
    }
    __syncthreads();
    const int nb = wave * 32;
    const double scl[4] = { 0x1p-33, 0x1p-25, 0x1p-17, 0x1p-9 };  // folds /4 pool
    double psum[2][2][4];
#pragma unroll
    for (int ml = 0; ml < 2; ++ml)
#pragma unroll
        for (int nt = 0; nt < 2; ++nt)
#pragma unroll
            for (int r = 0; r < 4; ++r) psum[ml][nt][r] = 0.0;
    for (int d = 0; d < 4; ++d) {
        v4i acc[2][2];
#pragma unroll
        for (int ml = 0; ml < 2; ++ml)
#pragma unroll
            for (int nt = 0; nt < 2; ++nt) acc[ml][nt] = (v4i){0, 0, 0, 0};
        v4i Bc[2], Bn[2];
#pragma unroll
        for (int nt = 0; nt < 2; ++nt)
            Bc[nt] = *(const v4i*)(Bd3 + (((size_t)(d * 18) * 256
                        + nb + nt * 16 + col) << 6) + quad * 16);
#pragma unroll 1
        for (int kk = 0; kk < 18; ++kk) {
            if (kk < 17) {
#pragma unroll
                for (int nt = 0; nt < 2; ++nt)
                    Bn[nt] = *(const v4i*)(Bd3 + (((size_t)(d * 18 + kk + 1) * 256
                                + nb + nt * 16 + col) << 6) + quad * 16);
            }
#pragma unroll
            for (int ml = 0; ml < 2; ++ml) {
                v4i Af = *(const v4i*)(As + (ml * 16 + col) * 1168 + kk * 64 + quad * 16);
#pragma unroll
                for (int nt = 0; nt < 2; ++nt)
                    acc[ml][nt] = __builtin_amdgcn_mfma_i32_16x16x64_i8(Af, Bc[nt], acc[ml][nt], 0, 0, 0);
            }
            if (kk < 17) {
#pragma unroll
                for (int nt = 0; nt < 2; ++nt) Bc[nt] = Bn[nt];
            }
        }
        double s = scl[d];
#pragma unroll
        for (int ml = 0; ml < 2; ++ml)
#pragma unroll
            for (int nt = 0; nt < 2; ++nt)
#pragma unroll
                for (int r = 0; r < 4; ++r)
                    psum[ml][nt][r] = fma((double)acc[ml][nt][r], s, psum[ml][nt][r]);
    }
#pragma unroll
    for (int ml = 0; ml < 2; ++ml)
#pragma unroll
        for (int nt = 0; nt < 2; ++nt) {
            double bias = (double)b3[nb + nt * 16 + col];
#pragma unroll
            for (int r = 0; r < 4; ++r) {
                int row = rbase + ml * 16 + quad * 4 + r;
                psp[(size_t)row * 256 + nb + nt * 16 + col] = bias + psum[ml][nt][r];
            }
        }
}

// ---------------- tc PSP: 4-digit i8 GEMM, 512 threads (8 waves, N=32/wave) -----
__global__ __launch_bounds__(512) void k_tcpsp(const unsigned char* __restrict__ s3,
        const signed char* __restrict__ Bdtc, const float* __restrict__ tcb,
        double* __restrict__ psp) {
    __shared__ __align__(16) unsigned char As[32 * 784];
    const int mt = blockIdx.x, rbase = mt * 32;
    const int t = rbase >> 8;                      // constant per block
    const int tid = threadIdx.x;
    const int wave = tid >> 6, lane = tid & 63;
    const int col = lane & 15, quad = lane >> 4;
    for (int c = tid; c < 1536; c += 512) {        // 32 rows x 48 chunks
        int row = c / 48, cho = c - row * 48;
        int j = cho >> 4, kc = (cho & 15) * 16;
        int bb = (rbase + row) & 255;
        int src = (t >= 2) ? (t - 2 + j) : ((j <= t) ? j : -1);  // j-th OLDEST tap
        v4i v = (v4i){0, 0, 0, 0};
        if (src >= 0) v = *(const v4i*)(s3 + ((size_t)(src * 256 + bb)) * 256 + kc);
        *(v4i*)(As + row * 784 + cho * 16) = v;
    }
    __syncthreads();
    const int nb = wave * 32;
    const double scl[4] = { 0x1p-31, 0x1p-23, 0x1p-15, 0x1p-7 };
    double psum[2][2][4];
#pragma unroll
    for (int ml = 0; ml < 2; ++ml)
#pragma unroll
        for (int nt = 0; nt < 2; ++nt)
#pragma unroll
            for (int r = 0; r < 4; ++r) psum[ml][nt][r] = 0.0;
    for (int d = 0; d < 4; ++d) {
        v4i acc[2][2];
#pragma unroll
        for (int ml = 0; ml < 2; ++ml)
#pragma unroll
            for (int nt = 0; nt < 2; ++nt) acc[ml][nt] = (v4i){0, 0, 0, 0};
        v4i Bc[2], Bn[2];
#pragma unroll
        for (int nt = 0; nt < 2; ++nt)
            Bc[nt] = *(const v4i*)(Bdtc + (((size_t)(d * 12) * 256
                        + nb + nt * 16 + col) << 6) + quad * 16);
#pragma unroll 1
        for (int kk = 0; kk < 12; ++kk) {
            if (kk < 11) {
#pragma unroll
                for (int nt = 0; nt < 2; ++nt)
                    Bn[nt] = *(const v4i*)(Bdtc + (((size_t)(d * 12 + kk + 1) * 256
                                + nb + nt * 16 + col) << 6) + quad * 16);
            }
#pragma unroll
            for (int ml = 0; ml < 2; ++ml) {
                v4i Af = *(const v4i*)(As + (ml * 16 + col) * 784 + kk * 64 + quad * 16);
#pragma unroll
                for (int nt = 0; nt < 2; ++nt)
                    acc[ml][nt] = __builtin_amdgcn_mfma_i32_16x16x64_i8(Af, Bc[nt], acc[ml][nt], 0, 0, 0);
            }
            if (kk < 11) {
#pragma unroll
                for (int nt = 0; nt < 2; ++nt) Bc[nt] = Bn[nt];
            }
        }
        double s = scl[d];
#pragma unroll
        for (int ml = 0; ml < 2; ++ml)
#pragma unroll
            for (int nt = 0; nt < 2; ++nt)
#pragma unroll
                for (int r = 0; r < 4; ++r)
                    psum[ml][nt][r] = fma((double)acc[ml][nt][r], s, psum[ml][nt][r]);
    }
#pragma unroll
    for (int ml = 0; ml < 2; ++ml)
#pragma unroll
        for (int nt = 0; nt < 2; ++nt) {
            int n = nb + nt * 16 + col;
            double bias = (double)tcb[n];
            if (t >= 1) bias += (double)tcb[256 + n];
            if (t >= 2) bias += (double)tcb[512 + n];
#pragma unroll
            for (int r = 0; r < 4; ++r) {
                int row = rbase + ml * 16 + quad * 4 + r;
                psp[(size_t)row * 256 + n] = bias + psum[ml][nt][r];
            }
        }
}

// ---------------- sequential LIF sweep over [T][B*256] fp64 psp -> spikes -------
__global__ __launch_bounds__(256) void k_lif_flat(const double* __restrict__ psp,
        unsigned char* __restrict__ out) {
    int n = blockIdx.x * 256 + threadIdx.x;
    double z[T];
#pragma unroll
    for (int t = 0; t < T; ++t)
        z[t] = psp[(size_t)t * 65536 + n];
    double cur = 0.0, vlt = 0.0;
    int spk = 0;
#pragma unroll
    for (int t = 0; t < T; ++t) {
        cur = 0.5 * cur + z[t];
        vlt = (spk ? 0.0 : 0.75 * vlt) + cur;
        spk = (vlt > 0.5) ? 1 : 0;
        out[(size_t)t * 65536 + n] = (unsigned char)spk;
    }
}

// ---------------- recurrent layer: 4-digit MFMA + FUSED tc-LIF pre-phase --------
// Pre-phase replaces the second k_lif_flat: each thread runs the 32-step tc
// LIF for its own 8 (b,oc) neurons straight from psptc, keeping the spike
// trains as 32-bit masks tcm[2][4] (8 VGPR). Bit-exact: same z values and op
// order as lif_flat. Transient LIF state dies before the Breg loads.
__global__ __launch_bounds__(512, 2) void k_recmm(const double* __restrict__ psptc,
        const signed char* __restrict__ Bdrec, const float* __restrict__ rb,
        unsigned char* __restrict__ rspk) {
    __shared__ __align__(16) unsigned char Abuf[2][16][272];
    const int g = blockIdx.x;
    const int tid = threadIdx.x;
    const int wv = tid >> 6, lane = tid & 63;
    const int col = lane & 15, quad = lane >> 4;

    for (int c = tid; c < 2176; c += 512) ((int*)Abuf)[c] = 0;

    // ---- fused tc LIF pre-phase ----
    unsigned tcm[2][4];
    {
        double c8[2][4], v8[2][4];
        int s8[2][4];
#pragma unroll
        for (int nt = 0; nt < 2; ++nt)
#pragma unroll
            for (int r = 0; r < 4; ++r) { c8[nt][r] = 0.0; v8[nt][r] = 0.0; s8[nt][r] = 0; tcm[nt][r] = 0u; }
        const double* pp = psptc + (size_t)(g * 16 + quad * 4) * 256 + wv * 32 + col;
#pragma unroll 1
        for (int t = 0; t < T; ++t) {
#pragma unroll
            for (int nt = 0; nt < 2; ++nt)
#pragma unroll
                for (int r = 0; r < 4; ++r) {
                    double z = pp[(size_t)t * 65536 + r * 256 + nt * 16];
                    c8[nt][r] = 0.5 * c8[nt][r] + z;
                    v8[nt][r] = (s8[nt][r] ? 0.0 : 0.75 * v8[nt][r]) + c8[nt][r];
                    s8[nt][r] = (v8[nt][r] > 0.5) ? 1 : 0;
                    tcm[nt][r] |= ((unsigned)s8[nt][r]) << t;
                }
        }
    }

    v4i Breg[2][4][4];
#pragma unroll
    for (int nt = 0; nt < 2; ++nt) {
        int ocb = wv * 32 + nt * 16 + col;
#pragma unroll
        for (int kc = 0; kc < 4; ++kc)
#pragma unroll
            for (int d = 0; d < 4; ++d)
                Breg[nt][kc][d] = *(const v4i*)(Bdrec + (size_t)d * 65536
                                                + ocb * 256 + kc * 64 + quad * 16);
    }
    double bias[2] = { (double)rb[wv * 32 + col], (double)rb[wv * 32 + 16 + col] };
    double cur[2][4], vlt[2][4];
    int spk[2][4];
#pragma unroll
    for (int nt = 0; nt < 2; ++nt)
#pragma unroll
        for (int r = 0; r < 4; ++r) { cur[nt][r] = 0.0; vlt[nt][r] = 0.0; spk[nt][r] = 0; }
    unsigned char* rsp = rspk + (size_t)(g * 16 + quad * 4) * 256 + wv * 32 + col;
    __syncthreads();

    for (int t = 0; t < T; ++t) {
        v4i Af[4];
#pragma unroll
        for (int kc = 0; kc < 4; ++kc)
            Af[kc] = *(const v4i*)(&Abuf[t & 1][col][kc * 64 + quad * 16]);
        v4i acc[2][4];
#pragma unroll
        for (int nt = 0; nt < 2; ++nt)
#pragma unroll
            for (int d = 0; d < 4; ++d) acc[nt][d] = (v4i){0, 0, 0, 0};
#pragma unroll
        for (int kc = 0; kc < 4; ++kc)
#pragma unroll
            for (int nt = 0; nt < 2; ++nt)
#pragma unroll
                for (int d = 0; d < 4; ++d)
                    acc[nt][d] = __builtin_amdgcn_mfma_i32_16x16x64_i8(Af[kc], Breg[nt][kc][d], acc[nt][d], 0, 0, 0);
#pragma unroll
        for (int nt = 0; nt < 2; ++nt)
#pragma unroll
            for (int r = 0; r < 4; ++r) {
                double v = (double)acc[nt][3][r];
                v = fma(v, 256.0, (double)acc[nt][2][r]);
                v = fma(v, 256.0, (double)acc[nt][1][r]);
                v = fma(v, 256.0, (double)acc[nt][0][r]);
                double tc = (double)((tcm[nt][r] >> t) & 1u);
                double z = fma(v, 0x1p-31, bias[nt]) + tc;
                cur[nt][r] = 0.5 * cur[nt][r] + z;
                vlt[nt][r] = (spk[nt][r] ? 0.0 : 0.75 * vlt[nt][r]) + cur[nt][r];
                int s = (vlt[nt][r] > 0.5) ? 1 : 0;
                spk[nt][r] = s;
                rsp[(size_t)t * 65536 + r * 256 + nt * 16] = (unsigned char)s;
                Abuf[(t + 1) & 1][quad * 4 + r][wv * 32 + nt * 16 + col] = (unsigned char)s;
            }
        __syncthreads();
    }
}

// ---------------- fc1 PSP: 4-digit i8 GEMM, 256 blocks x 32 rows ----------------
__global__ __launch_bounds__(256) void k_f1psp(const unsigned char* __restrict__ rspk,
        const signed char* __restrict__ Bdf1, const float* __restrict__ f1b,
        double* __restrict__ psp) {
    __shared__ __align__(16) unsigned char As[32 * 272];
    const int mt = blockIdx.x, rbase = mt * 32;
    const int tid = threadIdx.x;
    const int wave = tid >> 6, lane = tid & 63;
    const int col = lane & 15, quad = lane >> 4;
    for (int c = tid; c < 512; c += 256) {         // 32 rows x 16 chunks
        int row = c >> 4, cho = c & 15;
        v4i v = *(const v4i*)(rspk + (size_t)(rbase + row) * 256 + cho * 16);
        *(v4i*)(As + row * 272 + cho * 16) = v;
    }
    __syncthreads();
    const int nb = wave * 32;
    const double scl[4] = { 0x1p-31, 0x1p-23, 0x1p-15, 0x1p-7 };
    double psum[2][2][4];
#pragma unroll
    for (int ml = 0; ml < 2; ++ml)
#pragma unroll
        for (int nt = 0; nt < 2; ++nt)
#pragma unroll
            for (int r = 0; r < 4; ++r) psum[ml][nt][r] = 0.0;
    for (int d = 0; d < 4; ++d) {
        v4i acc[2][2];
#pragma unroll
        for (int ml = 0; ml < 2; ++ml)
#pragma unroll
            for (int nt = 0; nt < 2; ++nt) acc[ml][nt] = (v4i){0, 0, 0, 0};
#pragma unroll
        for (int kk = 0; kk < 4; ++kk) {
#pragma unroll
            for (int ml = 0; ml < 2; ++ml) {
                v4i Af = *(const v4i*)(As + (ml * 16 + col) * 272 + kk * 64 + quad * 16);
#pragma unroll
                for (int nt = 0; nt < 2; ++nt) {
                    v4i Bf = *(const v4i*)(Bdf1 + (((size_t)(d * 4 + kk) * 128
                            + nb + nt * 16 + col) << 6) + quad * 16);
                    acc[ml][nt] = __builtin_amdgcn_mfma_i32_16x16x64_i8(Af, Bf, acc[ml][nt], 0, 0, 0);
                }
            }
        }
        double s = scl[d];
#pragma unroll
        for (int ml = 0; ml < 2; ++ml)
#pragma unroll
            for (int nt = 0; nt < 2; ++nt)
#pragma unroll
                for (int r = 0; r < 4; ++r)
                    psum[ml][nt][r] = fma((double)acc[ml][nt][r], s, psum[ml][nt][r]);
    }
#pragma unroll
    for (int ml = 0; ml < 2; ++ml)
#pragma unroll
        for (int nt = 0; nt < 2; ++nt) {
            int n = nb + nt * 16 + col;
            double bias = (double)f1b[n];
#pragma unroll
            for (int r = 0; r < 4; ++r) {
                int row = rbase + ml * 16 + quad * 4 + r;
                psp[(size_t)row * 128 + n] = bias + psum[ml][nt][r];
            }
        }
}

// ---------------- fc1 LIF (registers) + fc2 via end-of-time reduction ----------
__global__ __launch_bounds__(128) void k_fc_out(const double* __restrict__ psp,
        const float* __restrict__ fc2w, const float* __restrict__ tsw,
        float* __restrict__ out) {
    __shared__ double sm[128];
    int b = blockIdx.x, oc = threadIdx.x;
    double ps[T];
#pragma unroll
    for (int t = 0; t < T; ++t)
        ps[t] = psp[((size_t)t * B + b) * 128 + oc];
    double cur = 0.0, vlt = 0.0, sAcc = 0.0;
    int spk = 0;
#pragma unroll
    for (int t = 0; t < T; ++t) {
        cur = 0.5 * cur + ps[t];
        vlt = (spk ? 0.0 : 0.75 * vlt) + cur;
        spk = (vlt > 0.5) ? 1 : 0;
        if (spk) sAcc += (double)tsw[t];
    }
    sm[oc] = sAcc;
    __syncthreads();
    if (oc < 2) {
        double s = 0.0;
        for (int k = 0; k < 128; ++k)
            s = fma(sm[k], (double)fc2w[oc * 128 + k], s);
        out[b * 2 + oc] = (float)s;
    }
}

extern "C" void kernel_launch(void* const* d_in, const int* in_sizes, int n_in,
                              void* d_out, int out_size, void* d_ws, size_t ws_size,
                              hipStream_t stream) {
    const float* x   = (const float*)d_in[0];
    const float* c1w = (const float*)d_in[1];
    const float* c1b = (const float*)d_in[2];
    const float* c2w = (const float*)d_in[3];
    const float* c2b = (const float*)d_in[4];
    const float* c3w = (const float*)d_in[5];
    const float* c3b = (const float*)d_in[6];
    const float* tcw = (const float*)d_in[7];
    const float* tcb = (const float*)d_in[8];
    const float* rcw = (const float*)d_in[9];
    const float* rcb = (const float*)d_in[10];
    const float* f1w = (const float*)d_in[11];
    const float* f1b = (const float*)d_in[12];
    const float* f2w = (const float*)d_in[13];
    const float* tsw = (const float*)d_in[14];

    char* ws = (char*)d_ws;
    signed char* Bd2      = (signed char*)(ws + OFF_BD2);
    signed char* Bd3      = (signed char*)(ws + OFF_BD3);
    signed char* Bdtc     = (signed char*)(ws + OFF_BDTC);
    signed char* Bdf1     = (signed char*)(ws + OFF_BDF1);
    signed char* Bdrec    = (signed char*)(ws + OFF_BDREC);
    unsigned char* s1     = (unsigned char*)(ws + OFF_S1);
    unsigned char* pool   = (unsigned char*)(ws + OFF_POOL);
    double* psp3          = (double*)(ws + OFF_PSP3);
    unsigned char* s3     = (unsigned char*)(ws + OFF_S3);
    double* psptc         = (double*)(ws + OFF_PSPTC);
    unsigned char* rsp    = (unsigned char*)(ws + OFF_R);
    double* pspf1         = (double*)(ws + OFF_PSPF1);

    k_prep_conv1<<<3616, 256, 0, stream>>>(x, c1w, c1b, s1,
                                           c2w, c3w, tcw, f1w, rcw,
                                           Bd2, Bd3, Bdtc, Bdf1, Bdrec);
    k_conv2   <<<2304, 256, 0, stream>>>(s1, Bd2, c2b, pool);
    k_c3psp   <<<256,  512, 0, stream>>>(pool, Bd3, c3b, psp3);
    k_lif_flat<<<256,  256, 0, stream>>>(psp3, s3);
    k_tcpsp   <<<256,  512, 0, stream>>>(s3, Bdtc, tcb, psptc);
    k_recmm   <<<16,   512, 0, stream>>>(psptc, Bdrec, rcb, rsp);
    k_f1psp   <<<256,  256, 0, stream>>>(rsp, Bdf1, f1b, pspf1);
    k_fc_out  <<<256,  128, 0, stream>>>(pspf1, f2w, tsw, (float*)d_out);
}

// Round 16
// 353.006 us; speedup vs baseline: 1.0325x; 1.0325x over previous
//
#include <hip/hip_runtime.h>

#define T 32
#define B 256

typedef int v4i __attribute__((ext_vector_type(4)));

// ---------------- workspace byte offsets ----------------
#define OFF_BD2   0            // int8 [4][9][128][64]  conv2 digits    (5-plane slot)
#define OFF_BD3   368640       // int8 [4][18][256][64] conv3 digits
#define OFF_BDTC  1843200      // int8 [4][12][256][64] tc digits
#define OFF_BDF1  2826240      // int8 [4][4][128][64]  fc1 digits
#define OFF_BDREC 2990080      // int8 [4][256][256]   rec digits
#define OFF_S1    3514368      // uchar [T][B][pix64][ic64]           33,554,432
#define OFF_POOL  37068800     // uchar [w9][t32][b256][oc128]         9,437,184
#define OFF_PSP3  46505984     // double [8192][256]                  16,777,216
#define OFF_S3    63283200     // uchar [t][b][256]                    2,097,152
#define OFF_PSPTC 65380352     // double [8192][256]                  16,777,216
#define OFF_TC    82157568     // uchar [t][b][256]                    2,097,152
#define OFF_R     84254720     // uchar [t][b][256]                    2,097,152
#define OFF_PSPF1 OFF_PSPTC    // double [8192][128] — reuses psptc (retired)
// total 86,351,872 bytes

// ---------------- fused prepd + conv1 (independent work, one dispatch) ----------
__global__ __launch_bounds__(256) void k_prep_conv1(const float* __restrict__ x,
        const float* __restrict__ w1, const float* __restrict__ b1,
        unsigned char* __restrict__ s1,
        const float* __restrict__ c2w, const float* __restrict__ c3w,
        const float* __restrict__ tcw, const float* __restrict__ f1w,
        const float* __restrict__ rcw,
        signed char* __restrict__ Bd2, signed char* __restrict__ Bd3,
        signed char* __restrict__ Bdtc, signed char* __restrict__ Bdf1,
        signed char* __restrict__ Bdrec) {
    __shared__ float xl[3200];              // [pos][t] (conv1 blocks only)
    if (blockIdx.x >= 1024) {               // ---- prepd path ----
        int idx = (blockIdx.x - 1024) * 256 + threadIdx.x;
        float w; signed char* base; int plane, off;
        if (idx < 73728) {                       // conv2: off = (kk*128+oc)*64+ic
            int oc = idx / 576, kpos = idx - oc * 576;
            int kk = kpos >> 6, ic = kpos & 63;
            int ky = kk / 3, kx = kk - ky * 3;
            w = c2w[((oc * 64 + ic) * 3 + ky) * 3 + kx];
            base = Bd2; plane = 73728; off = (kk * 128 + oc) * 64 + ic;
        } else if (idx < 368640) {               // conv3: k = win*128+ic
            int m = idx - 73728;
            int oc = m / 1152, kpos = m - oc * 1152;
            int win = kpos >> 7, ic = kpos & 127;
            w = c3w[(oc * 128 + ic) * 9 + win];
            base = Bd3; plane = 294912;
            off = ((kpos >> 6) * 256 + oc) * 64 + (kpos & 63);
        } else if (idx < 565248) {               // tc: k = j*256+kc
            int m = idx - 368640;
            int oc = m / 768, kpos = m - oc * 768;
            int j = kpos >> 8, kc = kpos & 255;
            w = tcw[(j * 256 + oc) * 256 + kc];
            base = Bdtc; plane = 196608;
            off = ((kpos >> 6) * 256 + oc) * 64 + (kpos & 63);
        } else if (idx < 598016) {               // fc1: k = kc
            int m = idx - 565248;
            int oc = m >> 8, kc = m & 255;
            w = f1w[oc * 256 + kc];
            base = Bdf1; plane = 32768;
            off = ((kc >> 6) * 128 + oc) * 64 + (kc & 63);
        } else if (idx < 663552) {               // rec: [d][oc][k]
            int m = idx - 598016;
            int oc = m >> 8, k = m & 255;
            w = rcw[oc * 256 + k];
            base = Bdrec; plane = 65536; off = m;
        } else return;
        long long W = (long long)rint((double)w * 2147483648.0);   // 2^31
#pragma unroll
        for (int d = 0; d < 3; ++d) {
            int dig = (int)(((W + 128) & 255) - 128);
            base[d * plane + off] = (signed char)dig;
            W = (W - dig) >> 8;
        }
        base[3 * plane + off] = (signed char)W;
        return;
    }
    // ---- conv1 path: LDS [pos][t] direct copy, t-vectorized taps ----
    int b  = blockIdx.x >> 2;
    int bp = blockIdx.x & 3;
    int oc = threadIdx.x & 63;
    int sub = threadIdx.x >> 6;             // 0..3
    const float* xb = x + b * 3200;         // input_data[b][0][10][10][T], t innermost
    for (int i = threadIdx.x; i < 3200; i += 256)
        xl[i] = xb[i];
    double wd[9];
#pragma unroll
    for (int j = 0; j < 9; ++j) wd[j] = (double)w1[oc * 9 + j];
    double bias = (double)b1[oc];
    __syncthreads();
    double cur[4], vlt[4];
    unsigned spkb = 0;
#pragma unroll
    for (int i = 0; i < 4; ++i) { cur[i] = 0.0; vlt[i] = 0.0; }
    const int pixbase = bp * 16 + sub * 4;
#pragma unroll 1
    for (int tb = 0; tb < 8; ++tb) {
#pragma unroll
        for (int i = 0; i < 4; ++i) {
            int pix = pixbase + i;
            int oy = pix >> 3, ox = pix & 7;
            double z0 = bias, z1 = bias, z2 = bias, z3 = bias;
#pragma unroll
            for (int ky = 0; ky < 3; ++ky)
#pragma unroll
                for (int kx = 0; kx < 3; ++kx) {
                    float4 v = *(const float4*)(&xl[((oy + ky) * 10 + ox + kx) * 32 + tb * 4]);
                    double w = wd[ky * 3 + kx];
                    z0 = fma(w, (double)v.x, z0);
                    z1 = fma(w, (double)v.y, z1);
                    z2 = fma(w, (double)v.z, z2);
                    z3 = fma(w, (double)v.w, z3);
                }
            double z[4] = { z0, z1, z2, z3 };
#pragma unroll
            for (int j = 0; j < 4; ++j) {
                int t = tb * 4 + j;
                cur[i] = 0.5 * cur[i] + z[j];
                int s = (spkb >> i) & 1;
                vlt[i] = (s ? 0.0 : 0.75 * vlt[i]) + cur[i];
                s = (vlt[i] > 0.5) ? 1 : 0;
                spkb = (spkb & ~(1u << i)) | ((unsigned)s << i);
                s1[((size_t)(t * B + b) * 64 + pix) * 64 + oc] = (unsigned char)s;
            }
        }
    }
}

// ---------------- conv2: single-pass 4-digit MFMA + in-register LIF ------------
// (R9 form — measured local optimum 98.7-99.5 µs.)
__global__ __launch_bounds__(256, 2) void k_conv2(const unsigned char* __restrict__ s1,
        const signed char* __restrict__ Bd2, const float* __restrict__ cb2,
        unsigned char* __restrict__ pooled) {
    __shared__ __align__(16) unsigned char As[32 * 1024];   // [t][swz(p,qo)][16]
    __shared__ unsigned smask[2][4][64];
    const int b = blockIdx.x / 9;
    const int w = blockIdx.x - b * 9;
    const int wy = w / 3, wx = w - wy * 3;
    const int tid = threadIdx.x;
    const int wave = tid >> 6, lane = tid & 63;
    const int col = lane & 15, quad = lane >> 4;
    const int m = lane & 15;
    const int px = m >> 2, tq = m & 3;          // A-row: px major, t minor
    const int py0 = px >> 1, px0 = px & 1;

    {   // stage A: p varies fastest across lanes (2-way-free write phases)
        const int pixbase = (2 * wy) * 8 + 2 * wx;
        for (int c = tid; c < 2048; c += 256) {
            int t = c >> 6, rem = c & 63;
            int p = rem & 15, qo = rem >> 4;
            int ly = p >> 2, lx = p & 3;
            int pix = pixbase + ly * 8 + lx;
            v4i v = *(const v4i*)(s1 + (((size_t)(t * B + b) * 64 + pix) << 6) + qo * 16);
            *(v4i*)(As + t * 1024 + ((qo * 16) + (p ^ (2 * (t & 3)))) * 16) = v;
        }
    }
    __syncthreads();

    for (int nh = 0; nh < 2; ++nh) {
        const int oc = nh * 64 + wave * 16 + col;
        const int boff = oc * 64 + quad * 16;       // lane offset within a kk slab
        v4i acc[8][4];
#pragma unroll
        for (int mt = 0; mt < 8; ++mt)
#pragma unroll
            for (int d = 0; d < 4; ++d) acc[mt][d] = (v4i){0, 0, 0, 0};
        v4i Bc[4], Bn[4];
#pragma unroll
        for (int d = 0; d < 4; ++d)
            Bc[d] = *(const v4i*)(Bd2 + (size_t)d * 73728 + boff);
#pragma unroll 1
        for (int kk = 0; kk < 9; ++kk) {
            if (kk < 8) {
#pragma unroll
                for (int d = 0; d < 4; ++d)
                    Bn[d] = *(const v4i*)(Bd2 + (size_t)d * 73728 + (kk + 1) * 8192 + boff);
            }
            const int ky = kk / 3, kx = kk - ky * 3;
            const int p = (py0 + ky) * 4 + (px0 + kx);
            const unsigned char* Ab = As + tq * 1024 + (quad * 16 + (p ^ (2 * tq))) * 16;
#pragma unroll
            for (int mt = 0; mt < 8; ++mt) {
                v4i Af = *(const v4i*)(Ab + mt * 4096);   // t = 4*mt + tq
#pragma unroll
                for (int d = 0; d < 4; ++d)
                    acc[mt][d] = __builtin_amdgcn_mfma_i32_16x16x64_i8(Af, Bc[d], acc[mt][d], 0, 0, 0);
            }
            if (kk < 8) {
#pragma unroll
                for (int d = 0; d < 4; ++d) Bc[d] = Bn[d];
            }
        }
        // in-register LIF: exact integer-pair recombine.
        double cur = 0.0, vlt = 0.0;
        int spk = 0;
        unsigned bits = 0;
        double bias = (double)cb2[oc];
#pragma unroll
        for (int mt = 0; mt < 8; ++mt)
#pragma unroll
            for (int r = 0; r < 4; ++r) {
                int lo = acc[mt][0][r] + (acc[mt][1][r] << 8);
                int hi = acc[mt][2][r] + (acc[mt][3][r] << 8);
                double v = fma((double)hi, 65536.0, (double)lo);
                double z = fma(v, 0x1p-31, bias);
                cur = 0.5 * cur + z;
                vlt = (spk ? 0.0 : 0.75 * vlt) + cur;
                spk = (vlt > 0.5) ? 1 : 0;
                bits |= ((unsigned)spk) << (mt * 4 + r);
            }
        smask[nh][quad][wave * 16 + col] = bits;
        __syncthreads();
        {   // avgpool: lane (quad,col) handles t = quad*8..quad*8+7 for its oc
            unsigned m0 = smask[nh][0][wave * 16 + col], m1 = smask[nh][1][wave * 16 + col];
            unsigned m2 = smask[nh][2][wave * 16 + col], m3 = smask[nh][3][wave * 16 + col];
#pragma unroll
            for (int q = 0; q < 8; ++q) {
                int t = quad * 8 + q;
                unsigned s = ((m0 >> t) & 1) + ((m1 >> t) & 1) + ((m2 >> t) & 1) + ((m3 >> t) & 1);
                pooled[(size_t)((w * 32 + t) * 256 + b) * 128 + oc] = (unsigned char)s;
            }
        }
    }
}

// ---------------- conv3 PSP: 4-digit i8 GEMM, 512 threads (8 waves, N=32/wave) --
__global__ __launch_bounds__(512) void k_c3psp(const unsigned char* __restrict__ pooled,
        const signed char* __restrict__ Bd3, const float* __restrict__ b3,
        double* __restrict__ psp) {
    __shared__ __align__(16) unsigned char As[32 * 1168];   // row pad 16
    const int mt = blockIdx.x, rbase = mt * 32;
    const int tid = threadIdx.x;
    const int wave = tid >> 6, lane = tid & 63;
    const int col = lane & 15, quad = lane >> 4;
    for (int c = tid; c < 2304; c += 512) {       // 32 rows x 72 chunks
        int row = c / 72, cho = c - row * 72;
        int wn = cho >> 3, ico = (cho & 7) * 16;
        v4i v = *(const v4i*)(pooled + ((size_t)(wn * 8192) + rbase + row) * 128 + ico);
        *(v4i*)(As + row * 1168 + cho * 16) = v;
    }
    __syncthreads();
    const int nb = wave * 32;
    const double scl[4] = { 0x1p-33, 0x1p-25, 0x1p-17, 0x1p-9 };  // folds /4 pool
    double psum[2][2][4];
#pragma unroll
    for (int ml = 0; ml < 2; ++ml)
#pragma unroll
        for (int nt = 0; nt < 2; ++nt)
#pragma unroll
            for (int r = 0; r < 4; ++r) psum[ml][nt][r] = 0.0;
    for (int d = 0; d < 4; ++d) {
        v4i acc[2][2];
#pragma unroll
        for (int ml = 0; ml < 2; ++ml)
#pragma unroll
            for (int nt = 0; nt < 2; ++nt) acc[ml][nt] = (v4i){0, 0, 0, 0};
        v4i Bc[2], Bn[2];
#pragma unroll
        for (int nt = 0; nt < 2; ++nt)
            Bc[nt] = *(const v4i*)(Bd3 + (((size_t)(d * 18) * 256
                        + nb + nt * 16 + col) << 6) + quad * 16);
#pragma unroll 1
        for (int kk = 0; kk < 18; ++kk) {
            if (kk < 17) {
#pragma unroll
                for (int nt = 0; nt < 2; ++nt)
                    Bn[nt] = *(const v4i*)(Bd3 + (((size_t)(d * 18 + kk + 1) * 256
                                + nb + nt * 16 + col) << 6) + quad * 16);
            }
#pragma unroll
            for (int ml = 0; ml < 2; ++ml) {
                v4i Af = *(const v4i*)(As + (ml * 16 + col) * 1168 + kk * 64 + quad * 16);
#pragma unroll
                for (int nt = 0; nt < 2; ++nt)
                    acc[ml][nt] = __builtin_amdgcn_mfma_i32_16x16x64_i8(Af, Bc[nt], acc[ml][nt], 0, 0, 0);
            }
            if (kk < 17) {
#pragma unroll
                for (int nt = 0; nt < 2; ++nt) Bc[nt] = Bn[nt];
            }
        }
        double s = scl[d];
#pragma unroll
        for (int ml = 0; ml < 2; ++ml)
#pragma unroll
            for (int nt = 0; nt < 2; ++nt)
#pragma unroll
                for (int r = 0; r < 4; ++r)
                    psum[ml][nt][r] = fma((double)acc[ml][nt][r], s, psum[ml][nt][r]);
    }
#pragma unroll
    for (int ml = 0; ml < 2; ++ml)
#pragma unroll
        for (int nt = 0; nt < 2; ++nt) {
            double bias = (double)b3[nb + nt * 16 + col];
#pragma unroll
            for (int r = 0; r < 4; ++r) {
                int row = rbase + ml * 16 + quad * 4 + r;
                psp[(size_t)row * 256 + nb + nt * 16 + col] = bias + psum[ml][nt][r];
            }
        }
}

// ---------------- tc PSP: 4-digit i8 GEMM, 512 threads (8 waves, N=32/wave) -----
__global__ __launch_bounds__(512) void k_tcpsp(const unsigned char* __restrict__ s3,
        const signed char* __restrict__ Bdtc, const float* __restrict__ tcb,
        double* __restrict__ psp) {
    __shared__ __align__(16) unsigned char As[32 * 784];
    const int mt = blockIdx.x, rbase = mt * 32;
    const int t = rbase >> 8;                      // constant per block
    const int tid = threadIdx.x;
    const int wave = tid >> 6, lane = tid & 63;
    const int col = lane & 15, quad = lane >> 4;
    for (int c = tid; c < 1536; c += 512) {        // 32 rows x 48 chunks
        int row = c / 48, cho = c - row * 48;
        int j = cho >> 4, kc = (cho & 15) * 16;
        int bb = (rbase + row) & 255;
        int src = (t >= 2) ? (t - 2 + j) : ((j <= t) ? j : -1);  // j-th OLDEST tap
        v4i v = (v4i){0, 0, 0, 0};
        if (src >= 0) v = *(const v4i*)(s3 + ((size_t)(src * 256 + bb)) * 256 + kc);
        *(v4i*)(As + row * 784 + cho * 16) = v;
    }
    __syncthreads();
    const int nb = wave * 32;
    const double scl[4] = { 0x1p-31, 0x1p-23, 0x1p-15, 0x1p-7 };
    double psum[2][2][4];
#pragma unroll
    for (int ml = 0; ml < 2; ++ml)
#pragma unroll
        for (int nt = 0; nt < 2; ++nt)
#pragma unroll
            for (int r = 0; r < 4; ++r) psum[ml][nt][r] = 0.0;
    for (int d = 0; d < 4; ++d) {
        v4i acc[2][2];
#pragma unroll
        for (int ml = 0; ml < 2; ++ml)
#pragma unroll
            for (int nt = 0; nt < 2; ++nt) acc[ml][nt] = (v4i){0, 0, 0, 0};
        v4i Bc[2], Bn[2];
#pragma unroll
        for (int nt = 0; nt < 2; ++nt)
            Bc[nt] = *(const v4i*)(Bdtc + (((size_t)(d * 12) * 256
                        + nb + nt * 16 + col) << 6) + quad * 16);
#pragma unroll 1
        for (int kk = 0; kk < 12; ++kk) {
            if (kk < 11) {
#pragma unroll
                for (int nt = 0; nt < 2; ++nt)
                    Bn[nt] = *(const v4i*)(Bdtc + (((size_t)(d * 12 + kk + 1) * 256
                                + nb + nt * 16 + col) << 6) + quad * 16);
            }
#pragma unroll
            for (int ml = 0; ml < 2; ++ml) {
                v4i Af = *(const v4i*)(As + (ml * 16 + col) * 784 + kk * 64 + quad * 16);
#pragma unroll
                for (int nt = 0; nt < 2; ++nt)
                    acc[ml][nt] = __builtin_amdgcn_mfma_i32_16x16x64_i8(Af, Bc[nt], acc[ml][nt], 0, 0, 0);
            }
            if (kk < 11) {
#pragma unroll
                for (int nt = 0; nt < 2; ++nt) Bc[nt] = Bn[nt];
            }
        }
        double s = scl[d];
#pragma unroll
        for (int ml = 0; ml < 2; ++ml)
#pragma unroll
            for (int nt = 0; nt < 2; ++nt)
#pragma unroll
                for (int r = 0; r < 4; ++r)
                    psum[ml][nt][r] = fma((double)acc[ml][nt][r], s, psum[ml][nt][r]);
    }
#pragma unroll
    for (int ml = 0; ml < 2; ++ml)
#pragma unroll
        for (int nt = 0; nt < 2; ++nt) {
            int n = nb + nt * 16 + col;
            double bias = (double)tcb[n];
            if (t >= 1) bias += (double)tcb[256 + n];
            if (t >= 2) bias += (double)tcb[512 + n];
#pragma unroll
            for (int r = 0; r < 4; ++r) {
                int row = rbase + ml * 16 + quad * 4 + r;
                psp[(size_t)row * 256 + n] = bias + psum[ml][nt][r];
            }
        }
}

// ---------------- sequential LIF sweep over [T][B*256] fp64 psp -> spikes -------
__global__ __launch_bounds__(256) void k_lif_flat(const double* __restrict__ psp,
        unsigned char* __restrict__ out) {
    int n = blockIdx.x * 256 + threadIdx.x;
    double z[T];
#pragma unroll
    for (int t = 0; t < T; ++t)
        z[t] = psp[(size_t)t * 65536 + n];
    double cur = 0.0, vlt = 0.0;
    int spk = 0;
#pragma unroll
    for (int t = 0; t < T; ++t) {
        cur = 0.5 * cur + z[t];
        vlt = (spk ? 0.0 : 0.75 * vlt) + cur;
        spk = (vlt > 0.5) ? 1 : 0;
        out[(size_t)t * 65536 + n] = (unsigned char)spk;
    }
}

// ---------------- recurrent layer: 4-digit MFMA, ALL weights in registers -------
__global__ __launch_bounds__(512, 2) void k_recmm(const unsigned char* __restrict__ tcspk,
        const signed char* __restrict__ Bdrec, const float* __restrict__ rb,
        unsigned char* __restrict__ rspk) {
    __shared__ __align__(16) unsigned char Abuf[2][16][272];
    const int g = blockIdx.x;
    const int tid = threadIdx.x;
    const int wv = tid >> 6, lane = tid & 63;
    const int col = lane & 15, quad = lane >> 4;

    for (int c = tid; c < 2176; c += 512) ((int*)Abuf)[c] = 0;

    v4i Breg[2][4][4];
#pragma unroll
    for (int nt = 0; nt < 2; ++nt) {
        int ocb = wv * 32 + nt * 16 + col;
#pragma unroll
        for (int kc = 0; kc < 4; ++kc)
#pragma unroll
            for (int d = 0; d < 4; ++d)
                Breg[nt][kc][d] = *(const v4i*)(Bdrec + (size_t)d * 65536
                                                + ocb * 256 + kc * 64 + quad * 16);
    }
    double bias[2] = { (double)rb[wv * 32 + col], (double)rb[wv * 32 + 16 + col] };
    double cur[2][4], vlt[2][4];
    int spk[2][4];
#pragma unroll
    for (int nt = 0; nt < 2; ++nt)
#pragma unroll
        for (int r = 0; r < 4; ++r) { cur[nt][r] = 0.0; vlt[nt][r] = 0.0; spk[nt][r] = 0; }
    const unsigned char* tcp = tcspk + (size_t)(g * 16 + quad * 4) * 256 + wv * 32 + col;
    unsigned char* rsp = rspk + (size_t)(g * 16 + quad * 4) * 256 + wv * 32 + col;
    __syncthreads();

    for (int t = 0; t < T; ++t) {
        unsigned char tcv[2][4];
#pragma unroll
        for (int nt = 0; nt < 2; ++nt)
#pragma unroll
            for (int r = 0; r < 4; ++r)
                tcv[nt][r] = tcp[(size_t)t * 65536 + r * 256 + nt * 16];
        v4i Af[4];
#pragma unroll
        for (int kc = 0; kc < 4; ++kc)
            Af[kc] = *(const v4i*)(&Abuf[t & 1][col][kc * 64 + quad * 16]);
        v4i acc[2][4];
#pragma unroll
        for (int nt = 0; nt < 2; ++nt)
#pragma unroll
            for (int d = 0; d < 4; ++d) acc[nt][d] = (v4i){0, 0, 0, 0};
#pragma unroll
        for (int kc = 0; kc < 4; ++kc)
#pragma unroll
            for (int nt = 0; nt < 2; ++nt)
#pragma unroll
                for (int d = 0; d < 4; ++d)
                    acc[nt][d] = __builtin_amdgcn_mfma_i32_16x16x64_i8(Af[kc], Breg[nt][kc][d], acc[nt][d], 0, 0, 0);
#pragma unroll
        for (int nt = 0; nt < 2; ++nt)
#pragma unroll
            for (int r = 0; r < 4; ++r) {
                double v = (double)acc[nt][3][r];
                v = fma(v, 256.0, (double)acc[nt][2][r]);
                v = fma(v, 256.0, (double)acc[nt][1][r]);
                v = fma(v, 256.0, (double)acc[nt][0][r]);
                double z = fma(v, 0x1p-31, bias[nt]) + (double)tcv[nt][r];
                cur[nt][r] = 0.5 * cur[nt][r] + z;
                vlt[nt][r] = (spk[nt][r] ? 0.0 : 0.75 * vlt[nt][r]) + cur[nt][r];
                int s = (vlt[nt][r] > 0.5) ? 1 : 0;
                spk[nt][r] = s;
                rsp[(size_t)t * 65536 + r * 256 + nt * 16] = (unsigned char)s;
                Abuf[(t + 1) & 1][quad * 4 + r][wv * 32 + nt * 16 + col] = (unsigned char)s;
            }
        __syncthreads();
    }
}

// ---------------- fc1 PSP: 4-digit i8 GEMM, 256 blocks x 32 rows ----------------
__global__ __launch_bounds__(256) void k_f1psp(const unsigned char* __restrict__ rspk,
        const signed char* __restrict__ Bdf1, const float* __restrict__ f1b,
        double* __restrict__ psp) {
    __shared__ __align__(16) unsigned char As[32 * 272];
    const int mt = blockIdx.x, rbase = mt * 32;
    const int tid = threadIdx.x;
    const int wave = tid >> 6, lane = tid & 63;
    const int col = lane & 15, quad = lane >> 4;
    for (int c = tid; c < 512; c += 256) {         // 32 rows x 16 chunks
        int row = c >> 4, cho = c & 15;
        v4i v = *(const v4i*)(rspk + (size_t)(rbase + row) * 256 + cho * 16);
        *(v4i*)(As + row * 272 + cho * 16) = v;
    }
    __syncthreads();
    const int nb = wave * 32;
    const double scl[4] = { 0x1p-31, 0x1p-23, 0x1p-15, 0x1p-7 };
    double psum[2][2][4];
#pragma unroll
    for (int ml = 0; ml < 2; ++ml)
#pragma unroll
        for (int nt = 0; nt < 2; ++nt)
#pragma unroll
            for (int r = 0; r < 4; ++r) psum[ml][nt][r] = 0.0;
    for (int d = 0; d < 4; ++d) {
        v4i acc[2][2];
#pragma unroll
        for (int ml = 0; ml < 2; ++ml)
#pragma unroll
            for (int nt = 0; nt < 2; ++nt) acc[ml][nt] = (v4i){0, 0, 0, 0};
#pragma unroll
        for (int kk = 0; kk < 4; ++kk) {
#pragma unroll
            for (int ml = 0; ml < 2; ++ml) {
                v4i Af = *(const v4i*)(As + (ml * 16 + col) * 272 + kk * 64 + quad * 16);
#pragma unroll
                for (int nt = 0; nt < 2; ++nt) {
                    v4i Bf = *(const v4i*)(Bdf1 + (((size_t)(d * 4 + kk) * 128
                            + nb + nt * 16 + col) << 6) + quad * 16);
                    acc[ml][nt] = __builtin_amdgcn_mfma_i32_16x16x64_i8(Af, Bf, acc[ml][nt], 0, 0, 0);
                }
            }
        }
        double s = scl[d];
#pragma unroll
        for (int ml = 0; ml < 2; ++ml)
#pragma unroll
            for (int nt = 0; nt < 2; ++nt)
#pragma unroll
                for (int r = 0; r < 4; ++r)
                    psum[ml][nt][r] = fma((double)acc[ml][nt][r], s, psum[ml][nt][r]);
    }
#pragma unroll
    for (int ml = 0; ml < 2; ++ml)
#pragma unroll
        for (int nt = 0; nt < 2; ++nt) {
            int n = nb + nt * 16 + col;
            double bias = (double)f1b[n];
#pragma unroll
            for (int r = 0; r < 4; ++r) {
                int row = rbase + ml * 16 + quad * 4 + r;
                psp[(size_t)row * 128 + n] = bias + psum[ml][nt][r];
            }
        }
}

// ---------------- fc1 LIF (registers) + fc2 via end-of-time reduction ----------
__global__ __launch_bounds__(128) void k_fc_out(const double* __restrict__ psp,
        const float* __restrict__ fc2w, const float* __restrict__ tsw,
        float* __restrict__ out) {
    __shared__ double sm[128];
    int b = blockIdx.x, oc = threadIdx.x;
    double ps[T];
#pragma unroll
    for (int t = 0; t < T; ++t)
        ps[t] = psp[((size_t)t * B + b) * 128 + oc];
    double cur = 0.0, vlt = 0.0, sAcc = 0.0;
    int spk = 0;
#pragma unroll
    for (int t = 0; t < T; ++t) {
        cur = 0.5 * cur + ps[t];
        vlt = (spk ? 0.0 : 0.75 * vlt) + cur;
        spk = (vlt > 0.5) ? 1 : 0;
        if (spk) sAcc += (double)tsw[t];
    }
    sm[oc] = sAcc;
    __syncthreads();
    if (oc < 2) {
        double s = 0.0;
        for (int k = 0; k < 128; ++k)
            s = fma(sm[k], (double)fc2w[oc * 128 + k], s);
        out[b * 2 + oc] = (float)s;
    }
}

extern "C" void kernel_launch(void* const* d_in, const int* in_sizes, int n_in,
                              void* d_out, int out_size, void* d_ws, size_t ws_size,
                              hipStream_t stream) {
    const float* x   = (const float*)d_in[0];
    const float* c1w = (const float*)d_in[1];
    const float* c1b = (const float*)d_in[2];
    const float* c2w = (const float*)d_in[3];
    const float* c2b = (const float*)d_in[4];
    const float* c3w = (const float*)d_in[5];
    const float* c3b = (const float*)d_in[6];
    const float* tcw = (const float*)d_in[7];
    const float* tcb = (const float*)d_in[8];
    const float* rcw = (const float*)d_in[9];
    const float* rcb = (const float*)d_in[10];
    const float* f1w = (const float*)d_in[11];
    const float* f1b = (const float*)d_in[12];
    const float* f2w = (const float*)d_in[13];
    const float* tsw = (const float*)d_in[14];

    char* ws = (char*)d_ws;
    signed char* Bd2      = (signed char*)(ws + OFF_BD2);
    signed char* Bd3      = (signed char*)(ws + OFF_BD3);
    signed char* Bdtc     = (signed char*)(ws + OFF_BDTC);
    signed char* Bdf1     = (signed char*)(ws + OFF_BDF1);
    signed char* Bdrec    = (signed char*)(ws + OFF_BDREC);
    unsigned char* s1     = (unsigned char*)(ws + OFF_S1);
    unsigned char* pool   = (unsigned char*)(ws + OFF_POOL);
    double* psp3          = (double*)(ws + OFF_PSP3);
    unsigned char* s3     = (unsigned char*)(ws + OFF_S3);
    double* psptc         = (double*)(ws + OFF_PSPTC);
    unsigned char* tcs    = (unsigned char*)(ws + OFF_TC);
    unsigned char* rsp    = (unsigned char*)(ws + OFF_R);
    double* pspf1         = (double*)(ws + OFF_PSPF1);

    k_prep_conv1<<<3616, 256, 0, stream>>>(x, c1w, c1b, s1,
                                           c2w, c3w, tcw, f1w, rcw,
                                           Bd2, Bd3, Bdtc, Bdf1, Bdrec);
    k_conv2   <<<2304, 256, 0, stream>>>(s1, Bd2, c2b, pool);
    k_c3psp   <<<256,  512, 0, stream>>>(pool, Bd3, c3b, psp3);
    k_lif_flat<<<256,  256, 0, stream>>>(psp3, s3);
    k_tcpsp   <<<256,  512, 0, stream>>>(s3, Bdtc, tcb, psptc);
    k_lif_flat<<<256,  256, 0, stream>>>(psptc, tcs);
    k_recmm   <<<16,   512, 0, stream>>>(tcs, Bdrec, rcb, rsp);
    k_f1psp   <<<256,  256, 0, stream>>>(rsp, Bdf1, f1b, pspf1);
    k_fc_out  <<<256,  128, 0, stream>>>(pspf1, f2w, tsw, (float*)d_out);
}